// Round 16
// baseline (276.899 us; speedup 1.0000x reference)
//
#include <hip/hip_runtime.h>
#include <cstdint>

// ---------------------------------------------------------------------------
// EncoderLayer (B=4, S=2048, D=768, H=12, FF=3072) on MI355X / gfx950.
// bf16 MFMA everywhere. GEMM: BM=128, BN template {128,64}, BK=64, 2-phase
// double-buffered LDS pipeline, XOR-swizzled LDS, XCD-chunked block swizzle,
// LDS-bounce epilogue; QKV-GEMM writes the V third transposed to vT.
// Attention: 32x32x16 MFMA, KVBLK=64, unshifted softmax, 4-way lrun
// partials, permlane P frags, coalesced ctx write via per-wave LDS bounce.
// prep_all: weight transposes + mask pack + LN1 fused in one launch.
// ---------------------------------------------------------------------------

typedef __bf16 bf16_t;
typedef __bf16 bf16x8 __attribute__((ext_vector_type(8)));
typedef __bf16 bf16x4 __attribute__((ext_vector_type(4)));
typedef __bf16 bf16x2 __attribute__((ext_vector_type(2)));
typedef float  f32x4  __attribute__((ext_vector_type(4)));
typedef float  f32x16 __attribute__((ext_vector_type(16)));

#define LOG2E 1.44269504088896340736f

__device__ __forceinline__ float exp2_fast(float x) {
  float r;
  asm("v_exp_f32 %0, %1" : "=v"(r) : "v"(x));
  return r;
}

__device__ __forceinline__ f32x4 mfma16(bf16x8 a, bf16x8 b, f32x4 c) {
  return __builtin_amdgcn_mfma_f32_16x16x32_bf16(a, b, c, 0, 0, 0);
}
__device__ __forceinline__ f32x16 mfma32(bf16x8 a, bf16x8 b, f32x16 c) {
  return __builtin_amdgcn_mfma_f32_32x32x16_bf16(a, b, c, 0, 0, 0);
}

__device__ __forceinline__ void gload16(const bf16_t* gsrc, bf16_t* lds) {
  __builtin_amdgcn_global_load_lds(
      (const __attribute__((address_space(1))) unsigned int*)(uintptr_t)gsrc,
      (__attribute__((address_space(3))) unsigned int*)(uintptr_t)lds,
      16, 0, 0);
}

__device__ __forceinline__ unsigned pk2(float a, float b) {
  bf16x2 v = {(bf16_t)a, (bf16_t)b};
  return __builtin_bit_cast(unsigned, v);
}
__device__ __forceinline__ void pl32_swap(unsigned& a, unsigned& b) {
  asm("v_permlane32_swap_b32 %0, %1" : "+v"(a), "+v"(b));
}
__device__ __forceinline__ bf16x8 frag4(unsigned w0, unsigned w1,
                                        unsigned w2, unsigned w3) {
  union { unsigned u[4]; bf16x8 v; } t;
  t.u[0] = w0; t.u[1] = w1; t.u[2] = w2; t.u[3] = w3;
  return t.v;
}

// ---------------------------------------------------------------------------
// Fused prep: [0,6912) weight transposes; [6912,23296) mask pack;
// [23296,25344) LN1 (independent of the other two; QKV-GEMM is the join).
// ---------------------------------------------------------------------------
__global__ __launch_bounds__(256) void prep_all(
    const float* __restrict__ wq, const float* __restrict__ wk,
    const float* __restrict__ wv, const float* __restrict__ wo,
    const float* __restrict__ w1, const float* __restrict__ w2,
    bf16_t* __restrict__ dst,
    const int* __restrict__ mask, unsigned int* __restrict__ bits,
    const float* __restrict__ x, const float* __restrict__ g1,
    const float* __restrict__ b1, bf16_t* __restrict__ hout)
{
  const int t = threadIdx.y * 32 + threadIdx.x;
  if (blockIdx.x >= 23296) {
    // ---- LN1: fp32 [8192,768] -> bf16, wave per row ----
    const int w = t >> 6, lane = t & 63;
    const int row = (blockIdx.x - 23296) * 4 + w;
    const float* xr = x + (size_t)row * 768;
    float4 v[3];
    float s = 0.f, s2 = 0.f;
#pragma unroll
    for (int p = 0; p < 3; ++p) {
      v[p] = *(const float4*)(xr + p * 256 + lane * 4);
      s  += v[p].x + v[p].y + v[p].z + v[p].w;
      s2 += v[p].x * v[p].x + v[p].y * v[p].y + v[p].z * v[p].z + v[p].w * v[p].w;
    }
#pragma unroll
    for (int m = 1; m <= 32; m <<= 1) {
      s  += __shfl_xor(s, m, 64);
      s2 += __shfl_xor(s2, m, 64);
    }
    const float mu  = s * (1.0f / 768.0f);
    const float var = s2 * (1.0f / 768.0f) - mu * mu;
    const float rs  = rsqrtf(var + 1e-5f);
    bf16_t* orow = hout + (size_t)row * 768;
#pragma unroll
    for (int p = 0; p < 3; ++p) {
      const float4 g4 = *(const float4*)(g1 + p * 256 + lane * 4);
      const float4 b4 = *(const float4*)(b1 + p * 256 + lane * 4);
      bf16x4 o = {(bf16_t)((v[p].x - mu) * rs * g4.x + b4.x),
                  (bf16_t)((v[p].y - mu) * rs * g4.y + b4.y),
                  (bf16_t)((v[p].z - mu) * rs * g4.z + b4.z),
                  (bf16_t)((v[p].w - mu) * rs * g4.w + b4.w)};
      *(bf16x4*)(orow + p * 256 + lane * 4) = o;
    }
    return;
  }
  if (blockIdx.x >= 6912) {
    // ---- mask pack: int32 [B,S,S] -> bits (bit=1 = masked) ----
    const int gid4 = (blockIdx.x - 6912) * 256 + t;
    const int4 v = ((const int4*)mask)[gid4];
    unsigned nib = (v.x != 0 ? 1u : 0u) | (v.y != 0 ? 2u : 0u) |
                   (v.z != 0 ? 4u : 0u) | (v.w != 0 ? 8u : 0u);
    nib <<= ((t & 7) * 4);
    nib |= __shfl_xor((int)nib, 1, 64);
    nib |= __shfl_xor((int)nib, 2, 64);
    nib |= __shfl_xor((int)nib, 4, 64);
    if ((t & 7) == 0) bits[gid4 >> 3] = nib;
    return;
  }
  // ---- weight transposes: Wt[n*K+k] = W[k*N+n] * scale ----
  __shared__ float tile[32][33];
  const int id = blockIdx.x;
  const float* W; size_t doff; int K, N, tx, local; float scale = 1.f;
  if (id < 576)       { W = wq; doff = 0;       K = 768;  N = 768;  tx = 24; local = id;        scale = 0.125f * LOG2E; }
  else if (id < 1152) { W = wk; doff = 589824;  K = 768;  N = 768;  tx = 24; local = id - 576;  }
  else if (id < 1728) { W = wv; doff = 1179648; K = 768;  N = 768;  tx = 24; local = id - 1152; }
  else if (id < 2304) { W = wo; doff = 1769472; K = 768;  N = 768;  tx = 24; local = id - 1728; }
  else if (id < 4608) { W = w1; doff = 2359296; K = 768;  N = 3072; tx = 96; local = id - 2304; }
  else                { W = w2; doff = 4718592; K = 3072; N = 768;  tx = 24; local = id - 4608; }
  const int n0 = (local % tx) * 32, k0 = (local / tx) * 32;
  const int tx_ = threadIdx.x, ty_ = threadIdx.y;
#pragma unroll
  for (int i = 0; i < 32; i += 8)
    tile[ty_ + i][tx_] = W[(size_t)(k0 + ty_ + i) * N + n0 + tx_];
  __syncthreads();
  bf16_t* const Wt = dst + doff;
#pragma unroll
  for (int i = 0; i < 32; i += 8)
    Wt[(size_t)(n0 + ty_ + i) * K + k0 + tx_] = (bf16_t)(tile[tx_][ty_ + i] * scale);
}

// ---------------------------------------------------------------------------
// LayerNorm (vectorized, wave-per-row): fp32 [8192,768] -> bf16 [8192,768]
// ---------------------------------------------------------------------------
__global__ __launch_bounds__(256) void ln_kernel(
    const float* __restrict__ xin, const float* __restrict__ gamma,
    const float* __restrict__ beta, bf16_t* __restrict__ outb)
{
  const int w = threadIdx.x >> 6, lane = threadIdx.x & 63;
  const int row = blockIdx.x * 4 + w;
  const float* xr = xin + (size_t)row * 768;
  float4 v[3];
  float s = 0.f, s2 = 0.f;
#pragma unroll
  for (int p = 0; p < 3; ++p) {
    v[p] = *(const float4*)(xr + p * 256 + lane * 4);
    s  += v[p].x + v[p].y + v[p].z + v[p].w;
    s2 += v[p].x * v[p].x + v[p].y * v[p].y + v[p].z * v[p].z + v[p].w * v[p].w;
  }
#pragma unroll
  for (int m = 1; m <= 32; m <<= 1) {
    s  += __shfl_xor(s, m, 64);
    s2 += __shfl_xor(s2, m, 64);
  }
  const float mu  = s * (1.0f / 768.0f);
  const float var = s2 * (1.0f / 768.0f) - mu * mu;
  const float rs  = rsqrtf(var + 1e-5f);
  bf16_t* orow = outb + (size_t)row * 768;
#pragma unroll
  for (int p = 0; p < 3; ++p) {
    const float4 g4 = *(const float4*)(gamma + p * 256 + lane * 4);
    const float4 b4 = *(const float4*)(beta  + p * 256 + lane * 4);
    bf16x4 o = {(bf16_t)((v[p].x - mu) * rs * g4.x + b4.x),
                (bf16_t)((v[p].y - mu) * rs * g4.y + b4.y),
                (bf16_t)((v[p].z - mu) * rs * g4.z + b4.z),
                (bf16_t)((v[p].w - mu) * rs * g4.w + b4.w)};
    *(bf16x4*)(orow + p * 256 + lane * 4) = o;
  }
}

// ---------------------------------------------------------------------------
// GEMM: C[M,N] = A[M,K] @ Bt[N,K]^T. BM=128, BN=BNT(128|64), BK=64, 4 waves.
// 2-phase pipeline. VOUT (BNT=128): bn >= 1536 writes transposed to vout.
// ---------------------------------------------------------------------------
template <bool RELU, bool OUT_F32, bool HAS_BIAS, bool HAS_RES, bool VOUT, int BNT>
__global__ __launch_bounds__(256) void gemm_kernel(
    const bf16_t* __restrict__ A, const bf16_t* __restrict__ Bt,
    void* __restrict__ Cout, const float* __restrict__ bias,
    const float* __restrict__ res, int Mdim, int Ndim, int Kdim,
    bf16_t* __restrict__ vout)
{
  constexpr int WCW = BNT / 2;
  constexpr int NJ  = WCW / 16;
  __shared__ __align__(16) bf16_t Smem[2 * (128 + BNT) * 64];
  const int tid = threadIdx.x;
  const int lane = tid & 63, w = tid >> 6;
  const int l15 = lane & 15, g = lane >> 4;
  const int gx = gridDim.x;
  const int nwg = gx * gridDim.y;
  const int p = blockIdx.y * gx + blockIdx.x;
  const int wg = (p & 7) * (nwg >> 3) + (p >> 3);
  const int bm = (wg / gx) * 128, bn = (wg % gx) * BNT;
  const int wr = (w >> 1) * 64, wc = (w & 1) * WCW;
  const int swz = l15 & 7;

  auto STAGE = [&](int kt, int buf) {
    const int k0 = kt << 6;
    bf16_t* const as = Smem + buf * (128 + BNT) * 64;
    bf16_t* const bs = as + 128 * 64;
#pragma unroll
    for (int it = 0; it < 4; ++it) {
      const int ch = it * 256 + tid;
      const int r = ch >> 3, c = ch & 7;
      gload16(A + (size_t)(bm + r) * Kdim + k0 + ((c ^ (r & 7)) * 8), as + ch * 8);
    }
#pragma unroll
    for (int it = 0; it < BNT / 32; ++it) {
      const int ch = it * 256 + tid;
      const int r = ch >> 3, c = ch & 7;
      gload16(Bt + (size_t)(bn + r) * Kdim + k0 + ((c ^ (r & 7)) * 8), bs + ch * 8);
    }
  };

  f32x4 acc[4][NJ] = {};
  const int nK = Kdim >> 6;
  STAGE(0, 0);
  __syncthreads();
  for (int kt = 0; kt < nK; ++kt) {
    const int cur = kt & 1;
    if (kt + 1 < nK) STAGE(kt + 1, cur ^ 1);
    const bf16_t* const As = Smem + cur * (128 + BNT) * 64;
    const bf16_t* const Bs = As + 128 * 64;
#pragma unroll
    for (int kk = 0; kk < 2; ++kk) {
      bf16x8 af[4], bfr[NJ];
#pragma unroll
      for (int i = 0; i < 4; ++i)
        af[i] = *(const bf16x8*)(As + (wr + i * 16 + l15) * 64 +
                                 (((kk * 4 + g) ^ swz) * 8));
#pragma unroll
      for (int j = 0; j < NJ; ++j)
        bfr[j] = *(const bf16x8*)(Bs + (wc + j * 16 + l15) * 64 +
                                  (((kk * 4 + g) ^ swz) * 8));
#pragma unroll
      for (int i = 0; i < 4; ++i)
#pragma unroll
        for (int j = 0; j < NJ; ++j)
          acc[i][j] = mfma16(af[i], bfr[j], acc[i][j]);
    }
    __syncthreads();
  }

  // ---- epilogue: LDS bounce -> vectorized stores ----
  if constexpr (!OUT_F32) {
    bf16_t* const wb = Smem + w * 4096;
    if (VOUT && bn >= 1536) {
#pragma unroll
      for (int i = 0; i < 4; ++i)
#pragma unroll
        for (int j = 0; j < NJ; ++j)
#pragma unroll
          for (int r = 0; r < 4; ++r) {
            const int srow = i * 16 + g * 4 + r;
            const int d = j * 16 + l15;
            *(bf16_t*)((char*)wb + d * 128 + ((srow * 2) ^ ((d & 7) << 4))) =
                (bf16_t)acc[i][j][r];
          }
      __syncthreads();
      const int b = bm >> 11;
      const int h = (bn + wc - 1536) >> 6;
      const int s0 = (bm & 2047) + wr;
      const int c = lane & 7;
#pragma unroll
      for (int ps = 0; ps < 8; ++ps) {
        const int drow = (lane >> 3) + ps * 8;
        bf16x8 v = *(const bf16x8*)((char*)wb + drow * 128 +
                                    ((c * 16) ^ ((drow & 7) << 4)));
        *(bf16x8*)(vout + ((size_t)((b * 12 + h) * 64 + drow)) * 2048 +
                   s0 + c * 8) = v;
      }
    } else {
#pragma unroll
      for (int i = 0; i < 4; ++i)
#pragma unroll
        for (int j = 0; j < NJ; ++j)
#pragma unroll
          for (int r = 0; r < 4; ++r) {
            const int row = i * 16 + g * 4 + r, col = j * 16 + l15;
            float v = acc[i][j][r];
            if constexpr (RELU) v = fmaxf(v, 0.f);
            *(bf16_t*)((char*)wb + row * 128 + ((col * 2) ^ ((row & 7) << 4))) =
                (bf16_t)v;
          }
      __syncthreads();
      bf16_t* const crow0 = (bf16_t*)Cout + (size_t)(bm + wr) * Ndim + bn + wc;
      const int c = lane & 7;
#pragma unroll
      for (int ps = 0; ps < 8; ++ps) {
        const int row = (lane >> 3) + ps * 8;
        bf16x8 v = *(const bf16x8*)((char*)wb + row * 128 +
                                    ((c * 16) ^ ((row & 7) << 4)));
        *(bf16x8*)(crow0 + (size_t)row * Ndim + c * 8) = v;
      }
    }
  } else {
    float* const fb = (float*)Smem + w * 2048;
    const int c = lane & 7;
#pragma unroll
    for (int jh = 0; jh < WCW / 32; ++jh) {
      if (jh) __syncthreads();
#pragma unroll
      for (int i = 0; i < 4; ++i)
#pragma unroll
        for (int jj = 0; jj < 2; ++jj)
#pragma unroll
          for (int r = 0; r < 4; ++r) {
            const int row = i * 16 + g * 4 + r, col = jj * 16 + l15;
            *(float*)((char*)fb + row * 128 + ((col * 4) ^ ((row & 7) << 4))) =
                acc[i][jh * 2 + jj][r];
          }
      __syncthreads();
      const int gcol = bn + wc + jh * 32 + c * 4;
      float4 bv = {0.f, 0.f, 0.f, 0.f};
      if constexpr (HAS_BIAS) bv = *(const float4*)(bias + gcol);
#pragma unroll
      for (int ps = 0; ps < 8; ++ps) {
        const int row = (lane >> 3) + ps * 8;
        float4 v = *(const float4*)((char*)fb + row * 128 +
                                    ((c * 16) ^ ((row & 7) << 4)));
        if constexpr (HAS_BIAS) { v.x += bv.x; v.y += bv.y; v.z += bv.z; v.w += bv.w; }
        if constexpr (HAS_RES) {
          const float4 rv = *(const float4*)(res + (size_t)(bm + wr + row) * Ndim + gcol);
          v.x += rv.x; v.y += rv.y; v.z += rv.z; v.w += rv.w;
        }
        *(float4*)((float*)Cout + (size_t)(bm + wr + row) * Ndim + gcol) = v;
      }
    }
  }
}

// ---------------------------------------------------------------------------
// Flash attention, 32x32 MFMA, KVBLK=64, 4 waves x 32 q. Unshifted softmax
// p=exp2(s); 4-way lrun partials; permlane P frags; coalesced ctx write via
// per-wave swizzled LDS bounce (no barrier needed; wave-private buffer).
// ---------------------------------------------------------------------------
__global__ __launch_bounds__(256, 4) void attn_kernel(
    const bf16_t* __restrict__ qkv, const bf16_t* __restrict__ vT,
    const unsigned int* __restrict__ mbits, bf16_t* __restrict__ ctx)
{
  __shared__ __align__(16) bf16_t KsBuf[2][64 * 64];   // [s=64][d=64] swizzled
  __shared__ __align__(16) bf16_t VsBuf[2][64 * 64];   // [d=64][s=64] swizzled
  __shared__ __align__(16) bf16_t Cs[4][32 * 64];      // per-wave ctx bounce
  const int tid = threadIdx.x;
  const int lane = tid & 63, w = tid >> 6;
  const int q32 = lane & 31, hi = lane >> 5;
  const int bh = blockIdx.x;      // bh-major => XCD = bh % 8 (K/V L2 affinity)
  const int qt = blockIdx.y;
  const int b = bh / 12, h = bh % 12;
  const int qabs = qt * 128 + w * 32 + q32;

  bf16x8 qf[4];
#pragma unroll
  for (int c = 0; c < 4; ++c)
    qf[c] = *(const bf16x8*)(qkv + (size_t)(b * 2048 + qabs) * 2304 +
                             h * 64 + c * 16 + hi * 8);

  auto stage = [&](bf16_t* ks, bf16_t* vs, int kt) {
    const size_t kb0 = (size_t)(b * 2048 + kt * 64);
#pragma unroll
    for (int it = 0; it < 2; ++it) {
      const int ch = it * 256 + tid;       // 0..511: K row s, 16B chunk (d)
      const int r = ch >> 3, c = ch & 7;
      gload16(qkv + (kb0 + r) * 2304 + 768 + h * 64 + ((c ^ (r & 7)) * 8), ks + ch * 8);
    }
#pragma unroll
    for (int it = 0; it < 2; ++it) {
      const int ch = it * 256 + tid;       // 0..511: V^T row d, 16B chunk (s)
      const int r = ch >> 3, c = ch & 7;
      gload16(vT + (size_t)(bh * 64 + r) * 2048 + kt * 64 + ((c ^ (r & 7)) * 8),
              vs + ch * 8);
    }
  };

  f32x16 oacc[2] = {};
  float lr0 = 0.f, lr1 = 0.f, lr2 = 0.f, lr3 = 0.f;

  stage(KsBuf[0], VsBuf[0], 0);
  __syncthreads();

  for (int kt = 0; kt < 32; ++kt) {
    const bf16_t* ksc = (kt & 1) ? KsBuf[1] : KsBuf[0];
    const bf16_t* vsc = (kt & 1) ? VsBuf[1] : VsBuf[0];
    if (kt < 31)
      stage((kt & 1) ? KsBuf[0] : KsBuf[1], (kt & 1) ? VsBuf[0] : VsBuf[1], kt + 1);

    const uint2 mm = *(const uint2*)(mbits + (size_t)(b * 2048 + qabs) * 64 + kt * 2);
    const unsigned mwv[2] = {mm.x >> (hi * 4), mm.y >> (hi * 4)};

    // ---- S^T = K @ Q^T from LDS: sacc[kb] = 32k x 32q tile ----
    f32x16 sacc[2] = {};
#pragma unroll
    for (int c = 0; c < 4; ++c) {
#pragma unroll
      for (int kb = 0; kb < 2; ++kb) {
        const int row = kb * 32 + q32;
        const int slot = (2 * c + hi) ^ (row & 7);
        bf16x8 kf = *(const bf16x8*)(ksc + row * 64 + slot * 8);
        sacc[kb] = mfma32(kf, qf[c], sacc[kb]);
      }
    }

    // ---- unshifted exp + mask-to-zero + 4-way partial sums ----
#pragma unroll
    for (int kb = 0; kb < 2; ++kb) {
#pragma unroll
      for (int rq = 0; rq < 4; ++rq) {
        const unsigned sel = mwv[kb] >> (8 * rq);
        {
          const float e0 = exp2_fast(sacc[kb][rq * 4 + 0]);
          const float p0 = (sel & 1u) ? 0.f : e0;
          sacc[kb][rq * 4 + 0] = p0;  lr0 += p0;
          const float e1 = exp2_fast(sacc[kb][rq * 4 + 1]);
          const float p1 = ((sel >> 1) & 1u) ? 0.f : e1;
          sacc[kb][rq * 4 + 1] = p1;  lr1 += p1;
          const float e2 = exp2_fast(sacc[kb][rq * 4 + 2]);
          const float p2 = ((sel >> 2) & 1u) ? 0.f : e2;
          sacc[kb][rq * 4 + 2] = p2;  lr2 += p2;
          const float e3 = exp2_fast(sacc[kb][rq * 4 + 3]);
          const float p3 = ((sel >> 3) & 1u) ? 0.f : e3;
          sacc[kb][rq * 4 + 3] = p3;  lr3 += p3;
        }
      }
    }

    // ---- PV: O^T += V^T @ P, P frags via permlane32_swap ----
    __builtin_amdgcn_s_setprio(1);
#pragma unroll
    for (int kb = 0; kb < 2; ++kb) {
      unsigned u0 = pk2(sacc[kb][0],  sacc[kb][1]);
      unsigned u1 = pk2(sacc[kb][2],  sacc[kb][3]);
      unsigned u2 = pk2(sacc[kb][4],  sacc[kb][5]);
      unsigned u3 = pk2(sacc[kb][6],  sacc[kb][7]);
      unsigned u4 = pk2(sacc[kb][8],  sacc[kb][9]);
      unsigned u5 = pk2(sacc[kb][10], sacc[kb][11]);
      unsigned u6 = pk2(sacc[kb][12], sacc[kb][13]);
      unsigned u7 = pk2(sacc[kb][14], sacc[kb][15]);
      pl32_swap(u0, u2);  pl32_swap(u1, u3);
      pl32_swap(u4, u6);  pl32_swap(u5, u7);
      bf16x8 p0 = frag4(u0, u1, u2, u3);
      bf16x8 p1 = frag4(u4, u5, u6, u7);
#pragma unroll
      for (int ks = 0; ks < 2; ++ks) {
        const bf16x8 pf = ks ? p1 : p0;
        const int cg = kb * 4 + ks * 2 + hi;   // 0..7
#pragma unroll
        for (int dt = 0; dt < 2; ++dt) {
          const int row = dt * 32 + q32;
          bf16x8 vf = *(const bf16x8*)(vsc + row * 64 + ((cg ^ (row & 7)) * 8));
          oacc[dt] = mfma32(vf, pf, oacc[dt]);
        }
      }
    }
    __builtin_amdgcn_s_setprio(0);
    __syncthreads();
  }

  // combine partials + cross-half reduce, once
  float lrun = (lr0 + lr1) + (lr2 + lr3);
  lrun += __shfl_xor(lrun, 32, 64);
  const float inv = (lrun > 0.f) ? 1.f / lrun : 0.f;

  // ---- ctx write via per-wave swizzled LDS bounce (coalesced 128B rows) ----
  bf16_t* const cw = &Cs[w][0];              // [32 q][64 d], 128B rows
#pragma unroll
  for (int dt = 0; dt < 2; ++dt)
#pragma unroll
    for (int rq = 0; rq < 4; ++rq) {
      bf16x4 ov = {(bf16_t)(oacc[dt][rq * 4 + 0] * inv),
                   (bf16_t)(oacc[dt][rq * 4 + 1] * inv),
                   (bf16_t)(oacc[dt][rq * 4 + 2] * inv),
                   (bf16_t)(oacc[dt][rq * 4 + 3] * inv)};
      const int ob = (dt * 32 + rq * 8 + hi * 4) * 2;      // 0..120, 8B step
      *(bf16x4*)((char*)cw + q32 * 128 + (ob ^ ((q32 & 7) << 4))) = ov;
    }
  // wave-private buffer: RAW covered by compiler lgkmcnt, no barrier
  const int c8 = lane & 7, rr8 = lane >> 3;
  bf16_t* const cbase = ctx + (size_t)(b * 2048 + qt * 128 + w * 32) * 768 + h * 64;
#pragma unroll
  for (int ps = 0; ps < 4; ++ps) {
    const int rr = rr8 + ps * 8;
    bf16x8 v = *(const bf16x8*)((char*)cw + rr * 128 +
                                ((c8 * 16) ^ ((rr & 7) << 4)));
    *(bf16x8*)(cbase + (size_t)rr * 768 + c8 * 8) = v;
  }
}

// ---------------------------------------------------------------------------
// Host launcher
// ---------------------------------------------------------------------------
extern "C" void kernel_launch(void* const* d_in, const int* in_sizes, int n_in,
                              void* d_out, int out_size, void* d_ws, size_t ws_size,
                              hipStream_t stream) {
  const float* x  = (const float*)d_in[0];
  const int* mask = (const int*)d_in[1];
  const float* wq = (const float*)d_in[2];
  const float* wk = (const float*)d_in[3];
  const float* wv = (const float*)d_in[4];
  const float* wo = (const float*)d_in[5];
  const float* bo = (const float*)d_in[6];
  const float* w1 = (const float*)d_in[7];
  const float* w2 = (const float*)d_in[8];
  const float* g1 = (const float*)d_in[9];
  const float* b1 = (const float*)d_in[10];
  const float* g2 = (const float*)d_in[11];
  const float* b2 = (const float*)d_in[12];
  float* out = (float*)d_out;

  char* p = (char*)d_ws;
  bf16_t* WQKVT = (bf16_t*)p; p += (size_t)2304 * 768 * 2;
  bf16_t* WOT   = (bf16_t*)p; p += (size_t)768 * 768 * 2;
  bf16_t* W1T   = (bf16_t*)p; p += (size_t)3072 * 768 * 2;
  bf16_t* W2T   = (bf16_t*)p; p += (size_t)768 * 3072 * 2;
  unsigned int* MB = (unsigned int*)p; p += (size_t)4 * 2048 * 64 * 4;
  bf16_t* Hbuf  = (bf16_t*)p; p += (size_t)8192 * 768 * 2;
  float*  X2    = (float*)p;  p += (size_t)8192 * 768 * 4;
  bf16_t* QKV   = (bf16_t*)p; p += (size_t)8192 * 2304 * 2;
  bf16_t* CTX   = (bf16_t*)p;
  bf16_t* FFN   = QKV;          // overlays QKV (dead by FFN1)
  bf16_t* VT    = (bf16_t*)X2;  // overlays X2 (vT dead before WO writes X2)

  // fused: 6 weight transposes + mask pack + LN1 in one launch
  prep_all<<<6912 + 16384 + 2048, dim3(32, 8), 0, stream>>>(
      wq, wk, wv, wo, w1, w2, WQKVT, mask, MB, x, g1, b1, Hbuf);

  gemm_kernel<false, false, false, false, true, 128><<<dim3(18, 64), 256, 0, stream>>>(
      Hbuf, WQKVT, QKV, nullptr, nullptr, 8192, 2304, 768, VT);
  attn_kernel<<<dim3(48, 16), 256, 0, stream>>>(QKV, VT, MB, CTX);
  gemm_kernel<false, true, true, true, false, 64><<<dim3(12, 64), 256, 0, stream>>>(
      CTX, WOT, X2, bo, x, 8192, 768, 768, nullptr);

  ln_kernel<<<2048, 256, 0, stream>>>(X2, g2, b2, Hbuf);
  gemm_kernel<true, false, false, false, false, 128><<<dim3(24, 64), 256, 0, stream>>>(
      Hbuf, W1T, FFN, nullptr, nullptr, 8192, 3072, 768, nullptr);
  gemm_kernel<false, true, false, true, false, 64><<<dim3(12, 64), 256, 0, stream>>>(
      FFN, W2T, out, nullptr, X2, 8192, 768, 3072, nullptr);
}

// Round 17
// 253.931 us; speedup vs baseline: 1.0905x; 1.0905x over previous
//
#include <hip/hip_runtime.h>
#include <cstdint>

// ---------------------------------------------------------------------------
// EncoderLayer (B=4, S=2048, D=768, H=12, FF=3072) on MI355X / gfx950.
// bf16 MFMA everywhere. GEMM: BM=128, BN template {128,64}, BK=64, 2-phase
// double-buffered LDS pipeline, XOR-swizzled LDS, XCD-chunked block swizzle,
// LDS-bounce epilogue; QKV-GEMM writes the V third transposed to vT.
// Attention (round-15 exact epilogue): 32x32x16 MFMA, KVBLK=64, unshifted
// softmax, 4-way lrun partials, permlane P frags, direct ctx stores
// (LDS-bounce epilogue tried in r16: VGPR 64->88, occ 25->16% — net loss).
// prep_all: weight transposes + mask pack + LN1 fused (kept: ~-12 us).
// ---------------------------------------------------------------------------

typedef __bf16 bf16_t;
typedef __bf16 bf16x8 __attribute__((ext_vector_type(8)));
typedef __bf16 bf16x4 __attribute__((ext_vector_type(4)));
typedef __bf16 bf16x2 __attribute__((ext_vector_type(2)));
typedef float  f32x4  __attribute__((ext_vector_type(4)));
typedef float  f32x16 __attribute__((ext_vector_type(16)));

#define LOG2E 1.44269504088896340736f

__device__ __forceinline__ float exp2_fast(float x) {
  float r;
  asm("v_exp_f32 %0, %1" : "=v"(r) : "v"(x));
  return r;
}

__device__ __forceinline__ f32x4 mfma16(bf16x8 a, bf16x8 b, f32x4 c) {
  return __builtin_amdgcn_mfma_f32_16x16x32_bf16(a, b, c, 0, 0, 0);
}
__device__ __forceinline__ f32x16 mfma32(bf16x8 a, bf16x8 b, f32x16 c) {
  return __builtin_amdgcn_mfma_f32_32x32x16_bf16(a, b, c, 0, 0, 0);
}

__device__ __forceinline__ void gload16(const bf16_t* gsrc, bf16_t* lds) {
  __builtin_amdgcn_global_load_lds(
      (const __attribute__((address_space(1))) unsigned int*)(uintptr_t)gsrc,
      (__attribute__((address_space(3))) unsigned int*)(uintptr_t)lds,
      16, 0, 0);
}

__device__ __forceinline__ unsigned pk2(float a, float b) {
  bf16x2 v = {(bf16_t)a, (bf16_t)b};
  return __builtin_bit_cast(unsigned, v);
}
__device__ __forceinline__ void pl32_swap(unsigned& a, unsigned& b) {
  asm("v_permlane32_swap_b32 %0, %1" : "+v"(a), "+v"(b));
}
__device__ __forceinline__ bf16x8 frag4(unsigned w0, unsigned w1,
                                        unsigned w2, unsigned w3) {
  union { unsigned u[4]; bf16x8 v; } t;
  t.u[0] = w0; t.u[1] = w1; t.u[2] = w2; t.u[3] = w3;
  return t.v;
}

// ---------------------------------------------------------------------------
// Fused prep: [0,6912) weight transposes; [6912,23296) mask pack;
// [23296,25344) LN1 (independent of the other two; QKV-GEMM is the join).
// ---------------------------------------------------------------------------
__global__ __launch_bounds__(256) void prep_all(
    const float* __restrict__ wq, const float* __restrict__ wk,
    const float* __restrict__ wv, const float* __restrict__ wo,
    const float* __restrict__ w1, const float* __restrict__ w2,
    bf16_t* __restrict__ dst,
    const int* __restrict__ mask, unsigned int* __restrict__ bits,
    const float* __restrict__ x, const float* __restrict__ g1,
    const float* __restrict__ b1, bf16_t* __restrict__ hout)
{
  const int t = threadIdx.y * 32 + threadIdx.x;
  if (blockIdx.x >= 23296) {
    // ---- LN1: fp32 [8192,768] -> bf16, wave per row ----
    const int w = t >> 6, lane = t & 63;
    const int row = (blockIdx.x - 23296) * 4 + w;
    const float* xr = x + (size_t)row * 768;
    float4 v[3];
    float s = 0.f, s2 = 0.f;
#pragma unroll
    for (int p = 0; p < 3; ++p) {
      v[p] = *(const float4*)(xr + p * 256 + lane * 4);
      s  += v[p].x + v[p].y + v[p].z + v[p].w;
      s2 += v[p].x * v[p].x + v[p].y * v[p].y + v[p].z * v[p].z + v[p].w * v[p].w;
    }
#pragma unroll
    for (int m = 1; m <= 32; m <<= 1) {
      s  += __shfl_xor(s, m, 64);
      s2 += __shfl_xor(s2, m, 64);
    }
    const float mu  = s * (1.0f / 768.0f);
    const float var = s2 * (1.0f / 768.0f) - mu * mu;
    const float rs  = rsqrtf(var + 1e-5f);
    bf16_t* orow = hout + (size_t)row * 768;
#pragma unroll
    for (int p = 0; p < 3; ++p) {
      const float4 g4 = *(const float4*)(g1 + p * 256 + lane * 4);
      const float4 b4 = *(const float4*)(b1 + p * 256 + lane * 4);
      bf16x4 o = {(bf16_t)((v[p].x - mu) * rs * g4.x + b4.x),
                  (bf16_t)((v[p].y - mu) * rs * g4.y + b4.y),
                  (bf16_t)((v[p].z - mu) * rs * g4.z + b4.z),
                  (bf16_t)((v[p].w - mu) * rs * g4.w + b4.w)};
      *(bf16x4*)(orow + p * 256 + lane * 4) = o;
    }
    return;
  }
  if (blockIdx.x >= 6912) {
    // ---- mask pack: int32 [B,S,S] -> bits (bit=1 = masked) ----
    const int gid4 = (blockIdx.x - 6912) * 256 + t;
    const int4 v = ((const int4*)mask)[gid4];
    unsigned nib = (v.x != 0 ? 1u : 0u) | (v.y != 0 ? 2u : 0u) |
                   (v.z != 0 ? 4u : 0u) | (v.w != 0 ? 8u : 0u);
    nib <<= ((t & 7) * 4);
    nib |= __shfl_xor((int)nib, 1, 64);
    nib |= __shfl_xor((int)nib, 2, 64);
    nib |= __shfl_xor((int)nib, 4, 64);
    if ((t & 7) == 0) bits[gid4 >> 3] = nib;
    return;
  }
  // ---- weight transposes: Wt[n*K+k] = W[k*N+n] * scale ----
  __shared__ float tile[32][33];
  const int id = blockIdx.x;
  const float* W; size_t doff; int K, N, tx, local; float scale = 1.f;
  if (id < 576)       { W = wq; doff = 0;       K = 768;  N = 768;  tx = 24; local = id;        scale = 0.125f * LOG2E; }
  else if (id < 1152) { W = wk; doff = 589824;  K = 768;  N = 768;  tx = 24; local = id - 576;  }
  else if (id < 1728) { W = wv; doff = 1179648; K = 768;  N = 768;  tx = 24; local = id - 1152; }
  else if (id < 2304) { W = wo; doff = 1769472; K = 768;  N = 768;  tx = 24; local = id - 1728; }
  else if (id < 4608) { W = w1; doff = 2359296; K = 768;  N = 3072; tx = 96; local = id - 2304; }
  else                { W = w2; doff = 4718592; K = 3072; N = 768;  tx = 24; local = id - 4608; }
  const int n0 = (local % tx) * 32, k0 = (local / tx) * 32;
  const int tx_ = threadIdx.x, ty_ = threadIdx.y;
#pragma unroll
  for (int i = 0; i < 32; i += 8)
    tile[ty_ + i][tx_] = W[(size_t)(k0 + ty_ + i) * N + n0 + tx_];
  __syncthreads();
  bf16_t* const Wt = dst + doff;
#pragma unroll
  for (int i = 0; i < 32; i += 8)
    Wt[(size_t)(n0 + ty_ + i) * K + k0 + tx_] = (bf16_t)(tile[tx_][ty_ + i] * scale);
}

// ---------------------------------------------------------------------------
// LayerNorm (vectorized, wave-per-row): fp32 [8192,768] -> bf16 [8192,768]
// ---------------------------------------------------------------------------
__global__ __launch_bounds__(256) void ln_kernel(
    const float* __restrict__ xin, const float* __restrict__ gamma,
    const float* __restrict__ beta, bf16_t* __restrict__ outb)
{
  const int w = threadIdx.x >> 6, lane = threadIdx.x & 63;
  const int row = blockIdx.x * 4 + w;
  const float* xr = xin + (size_t)row * 768;
  float4 v[3];
  float s = 0.f, s2 = 0.f;
#pragma unroll
  for (int p = 0; p < 3; ++p) {
    v[p] = *(const float4*)(xr + p * 256 + lane * 4);
    s  += v[p].x + v[p].y + v[p].z + v[p].w;
    s2 += v[p].x * v[p].x + v[p].y * v[p].y + v[p].z * v[p].z + v[p].w * v[p].w;
  }
#pragma unroll
  for (int m = 1; m <= 32; m <<= 1) {
    s  += __shfl_xor(s, m, 64);
    s2 += __shfl_xor(s2, m, 64);
  }
  const float mu  = s * (1.0f / 768.0f);
  const float var = s2 * (1.0f / 768.0f) - mu * mu;
  const float rs  = rsqrtf(var + 1e-5f);
  bf16_t* orow = outb + (size_t)row * 768;
#pragma unroll
  for (int p = 0; p < 3; ++p) {
    const float4 g4 = *(const float4*)(gamma + p * 256 + lane * 4);
    const float4 b4 = *(const float4*)(beta  + p * 256 + lane * 4);
    bf16x4 o = {(bf16_t)((v[p].x - mu) * rs * g4.x + b4.x),
                (bf16_t)((v[p].y - mu) * rs * g4.y + b4.y),
                (bf16_t)((v[p].z - mu) * rs * g4.z + b4.z),
                (bf16_t)((v[p].w - mu) * rs * g4.w + b4.w)};
    *(bf16x4*)(orow + p * 256 + lane * 4) = o;
  }
}

// ---------------------------------------------------------------------------
// GEMM: C[M,N] = A[M,K] @ Bt[N,K]^T. BM=128, BN=BNT(128|64), BK=64, 4 waves.
// 2-phase pipeline. VOUT (BNT=128): bn >= 1536 writes transposed to vout.
// ---------------------------------------------------------------------------
template <bool RELU, bool OUT_F32, bool HAS_BIAS, bool HAS_RES, bool VOUT, int BNT>
__global__ __launch_bounds__(256) void gemm_kernel(
    const bf16_t* __restrict__ A, const bf16_t* __restrict__ Bt,
    void* __restrict__ Cout, const float* __restrict__ bias,
    const float* __restrict__ res, int Mdim, int Ndim, int Kdim,
    bf16_t* __restrict__ vout)
{
  constexpr int WCW = BNT / 2;
  constexpr int NJ  = WCW / 16;
  __shared__ __align__(16) bf16_t Smem[2 * (128 + BNT) * 64];
  const int tid = threadIdx.x;
  const int lane = tid & 63, w = tid >> 6;
  const int l15 = lane & 15, g = lane >> 4;
  const int gx = gridDim.x;
  const int nwg = gx * gridDim.y;
  const int p = blockIdx.y * gx + blockIdx.x;
  const int wg = (p & 7) * (nwg >> 3) + (p >> 3);
  const int bm = (wg / gx) * 128, bn = (wg % gx) * BNT;
  const int wr = (w >> 1) * 64, wc = (w & 1) * WCW;
  const int swz = l15 & 7;

  auto STAGE = [&](int kt, int buf) {
    const int k0 = kt << 6;
    bf16_t* const as = Smem + buf * (128 + BNT) * 64;
    bf16_t* const bs = as + 128 * 64;
#pragma unroll
    for (int it = 0; it < 4; ++it) {
      const int ch = it * 256 + tid;
      const int r = ch >> 3, c = ch & 7;
      gload16(A + (size_t)(bm + r) * Kdim + k0 + ((c ^ (r & 7)) * 8), as + ch * 8);
    }
#pragma unroll
    for (int it = 0; it < BNT / 32; ++it) {
      const int ch = it * 256 + tid;
      const int r = ch >> 3, c = ch & 7;
      gload16(Bt + (size_t)(bn + r) * Kdim + k0 + ((c ^ (r & 7)) * 8), bs + ch * 8);
    }
  };

  f32x4 acc[4][NJ] = {};
  const int nK = Kdim >> 6;
  STAGE(0, 0);
  __syncthreads();
  for (int kt = 0; kt < nK; ++kt) {
    const int cur = kt & 1;
    if (kt + 1 < nK) STAGE(kt + 1, cur ^ 1);
    const bf16_t* const As = Smem + cur * (128 + BNT) * 64;
    const bf16_t* const Bs = As + 128 * 64;
#pragma unroll
    for (int kk = 0; kk < 2; ++kk) {
      bf16x8 af[4], bfr[NJ];
#pragma unroll
      for (int i = 0; i < 4; ++i)
        af[i] = *(const bf16x8*)(As + (wr + i * 16 + l15) * 64 +
                                 (((kk * 4 + g) ^ swz) * 8));
#pragma unroll
      for (int j = 0; j < NJ; ++j)
        bfr[j] = *(const bf16x8*)(Bs + (wc + j * 16 + l15) * 64 +
                                  (((kk * 4 + g) ^ swz) * 8));
#pragma unroll
      for (int i = 0; i < 4; ++i)
#pragma unroll
        for (int j = 0; j < NJ; ++j)
          acc[i][j] = mfma16(af[i], bfr[j], acc[i][j]);
    }
    __syncthreads();
  }

  // ---- epilogue: LDS bounce -> vectorized stores ----
  if constexpr (!OUT_F32) {
    bf16_t* const wb = Smem + w * 4096;
    if (VOUT && bn >= 1536) {
#pragma unroll
      for (int i = 0; i < 4; ++i)
#pragma unroll
        for (int j = 0; j < NJ; ++j)
#pragma unroll
          for (int r = 0; r < 4; ++r) {
            const int srow = i * 16 + g * 4 + r;
            const int d = j * 16 + l15;
            *(bf16_t*)((char*)wb + d * 128 + ((srow * 2) ^ ((d & 7) << 4))) =
                (bf16_t)acc[i][j][r];
          }
      __syncthreads();
      const int b = bm >> 11;
      const int h = (bn + wc - 1536) >> 6;
      const int s0 = (bm & 2047) + wr;
      const int c = lane & 7;
#pragma unroll
      for (int ps = 0; ps < 8; ++ps) {
        const int drow = (lane >> 3) + ps * 8;
        bf16x8 v = *(const bf16x8*)((char*)wb + drow * 128 +
                                    ((c * 16) ^ ((drow & 7) << 4)));
        *(bf16x8*)(vout + ((size_t)((b * 12 + h) * 64 + drow)) * 2048 +
                   s0 + c * 8) = v;
      }
    } else {
#pragma unroll
      for (int i = 0; i < 4; ++i)
#pragma unroll
        for (int j = 0; j < NJ; ++j)
#pragma unroll
          for (int r = 0; r < 4; ++r) {
            const int row = i * 16 + g * 4 + r, col = j * 16 + l15;
            float v = acc[i][j][r];
            if constexpr (RELU) v = fmaxf(v, 0.f);
            *(bf16_t*)((char*)wb + row * 128 + ((col * 2) ^ ((row & 7) << 4))) =
                (bf16_t)v;
          }
      __syncthreads();
      bf16_t* const crow0 = (bf16_t*)Cout + (size_t)(bm + wr) * Ndim + bn + wc;
      const int c = lane & 7;
#pragma unroll
      for (int ps = 0; ps < 8; ++ps) {
        const int row = (lane >> 3) + ps * 8;
        bf16x8 v = *(const bf16x8*)((char*)wb + row * 128 +
                                    ((c * 16) ^ ((row & 7) << 4)));
        *(bf16x8*)(crow0 + (size_t)row * Ndim + c * 8) = v;
      }
    }
  } else {
    float* const fb = (float*)Smem + w * 2048;
    const int c = lane & 7;
#pragma unroll
    for (int jh = 0; jh < WCW / 32; ++jh) {
      if (jh) __syncthreads();
#pragma unroll
      for (int i = 0; i < 4; ++i)
#pragma unroll
        for (int jj = 0; jj < 2; ++jj)
#pragma unroll
          for (int r = 0; r < 4; ++r) {
            const int row = i * 16 + g * 4 + r, col = jj * 16 + l15;
            *(float*)((char*)fb + row * 128 + ((col * 4) ^ ((row & 7) << 4))) =
                acc[i][jh * 2 + jj][r];
          }
      __syncthreads();
      const int gcol = bn + wc + jh * 32 + c * 4;
      float4 bv = {0.f, 0.f, 0.f, 0.f};
      if constexpr (HAS_BIAS) bv = *(const float4*)(bias + gcol);
#pragma unroll
      for (int ps = 0; ps < 8; ++ps) {
        const int row = (lane >> 3) + ps * 8;
        float4 v = *(const float4*)((char*)fb + row * 128 +
                                    ((c * 16) ^ ((row & 7) << 4)));
        if constexpr (HAS_BIAS) { v.x += bv.x; v.y += bv.y; v.z += bv.z; v.w += bv.w; }
        if constexpr (HAS_RES) {
          const float4 rv = *(const float4*)(res + (size_t)(bm + wr + row) * Ndim + gcol);
          v.x += rv.x; v.y += rv.y; v.z += rv.z; v.w += rv.w;
        }
        *(float4*)((float*)Cout + (size_t)(bm + wr + row) * Ndim + gcol) = v;
      }
    }
  }
}

// ---------------------------------------------------------------------------
// Flash attention (round-15 exact), 32x32 MFMA, KVBLK=64, 4 waves x 32 q.
// Unshifted softmax p=exp2(s); 4-way lrun partials; permlane P frags;
// direct ctx stores (bounce epilogue regressed occupancy — r16).
// ---------------------------------------------------------------------------
__global__ __launch_bounds__(256, 4) void attn_kernel(
    const bf16_t* __restrict__ qkv, const bf16_t* __restrict__ vT,
    const unsigned int* __restrict__ mbits, bf16_t* __restrict__ ctx)
{
  __shared__ __align__(16) bf16_t KsBuf[2][64 * 64];   // [s=64][d=64] swizzled
  __shared__ __align__(16) bf16_t VsBuf[2][64 * 64];   // [d=64][s=64] swizzled
  const int tid = threadIdx.x;
  const int lane = tid & 63, w = tid >> 6;
  const int q32 = lane & 31, hi = lane >> 5;
  const int bh = blockIdx.x;      // bh-major => XCD = bh % 8 (K/V L2 affinity)
  const int qt = blockIdx.y;
  const int b = bh / 12, h = bh % 12;
  const int qabs = qt * 128 + w * 32 + q32;

  bf16x8 qf[4];
#pragma unroll
  for (int c = 0; c < 4; ++c)
    qf[c] = *(const bf16x8*)(qkv + (size_t)(b * 2048 + qabs) * 2304 +
                             h * 64 + c * 16 + hi * 8);

  auto stage = [&](bf16_t* ks, bf16_t* vs, int kt) {
    const size_t kb0 = (size_t)(b * 2048 + kt * 64);
#pragma unroll
    for (int it = 0; it < 2; ++it) {
      const int ch = it * 256 + tid;       // 0..511: K row s, 16B chunk (d)
      const int r = ch >> 3, c = ch & 7;
      gload16(qkv + (kb0 + r) * 2304 + 768 + h * 64 + ((c ^ (r & 7)) * 8), ks + ch * 8);
    }
#pragma unroll
    for (int it = 0; it < 2; ++it) {
      const int ch = it * 256 + tid;       // 0..511: V^T row d, 16B chunk (s)
      const int r = ch >> 3, c = ch & 7;
      gload16(vT + (size_t)(bh * 64 + r) * 2048 + kt * 64 + ((c ^ (r & 7)) * 8),
              vs + ch * 8);
    }
  };

  f32x16 oacc[2] = {};
  float lr0 = 0.f, lr1 = 0.f, lr2 = 0.f, lr3 = 0.f;

  stage(KsBuf[0], VsBuf[0], 0);
  __syncthreads();

  for (int kt = 0; kt < 32; ++kt) {
    const bf16_t* ksc = (kt & 1) ? KsBuf[1] : KsBuf[0];
    const bf16_t* vsc = (kt & 1) ? VsBuf[1] : VsBuf[0];
    if (kt < 31)
      stage((kt & 1) ? KsBuf[0] : KsBuf[1], (kt & 1) ? VsBuf[0] : VsBuf[1], kt + 1);

    const uint2 mm = *(const uint2*)(mbits + (size_t)(b * 2048 + qabs) * 64 + kt * 2);
    const unsigned mwv[2] = {mm.x >> (hi * 4), mm.y >> (hi * 4)};

    // ---- S^T = K @ Q^T from LDS: sacc[kb] = 32k x 32q tile ----
    f32x16 sacc[2] = {};
#pragma unroll
    for (int c = 0; c < 4; ++c) {
#pragma unroll
      for (int kb = 0; kb < 2; ++kb) {
        const int row = kb * 32 + q32;
        const int slot = (2 * c + hi) ^ (row & 7);
        bf16x8 kf = *(const bf16x8*)(ksc + row * 64 + slot * 8);
        sacc[kb] = mfma32(kf, qf[c], sacc[kb]);
      }
    }

    // ---- unshifted exp + mask-to-zero + 4-way partial sums ----
#pragma unroll
    for (int kb = 0; kb < 2; ++kb) {
#pragma unroll
      for (int rq = 0; rq < 4; ++rq) {
        const unsigned sel = mwv[kb] >> (8 * rq);
        {
          const float e0 = exp2_fast(sacc[kb][rq * 4 + 0]);
          const float p0 = (sel & 1u) ? 0.f : e0;
          sacc[kb][rq * 4 + 0] = p0;  lr0 += p0;
          const float e1 = exp2_fast(sacc[kb][rq * 4 + 1]);
          const float p1 = ((sel >> 1) & 1u) ? 0.f : e1;
          sacc[kb][rq * 4 + 1] = p1;  lr1 += p1;
          const float e2 = exp2_fast(sacc[kb][rq * 4 + 2]);
          const float p2 = ((sel >> 2) & 1u) ? 0.f : e2;
          sacc[kb][rq * 4 + 2] = p2;  lr2 += p2;
          const float e3 = exp2_fast(sacc[kb][rq * 4 + 3]);
          const float p3 = ((sel >> 3) & 1u) ? 0.f : e3;
          sacc[kb][rq * 4 + 3] = p3;  lr3 += p3;
        }
      }
    }

    // ---- PV: O^T += V^T @ P, P frags via permlane32_swap ----
    __builtin_amdgcn_s_setprio(1);
#pragma unroll
    for (int kb = 0; kb < 2; ++kb) {
      unsigned u0 = pk2(sacc[kb][0],  sacc[kb][1]);
      unsigned u1 = pk2(sacc[kb][2],  sacc[kb][3]);
      unsigned u2 = pk2(sacc[kb][4],  sacc[kb][5]);
      unsigned u3 = pk2(sacc[kb][6],  sacc[kb][7]);
      unsigned u4 = pk2(sacc[kb][8],  sacc[kb][9]);
      unsigned u5 = pk2(sacc[kb][10], sacc[kb][11]);
      unsigned u6 = pk2(sacc[kb][12], sacc[kb][13]);
      unsigned u7 = pk2(sacc[kb][14], sacc[kb][15]);
      pl32_swap(u0, u2);  pl32_swap(u1, u3);
      pl32_swap(u4, u6);  pl32_swap(u5, u7);
      bf16x8 p0 = frag4(u0, u1, u2, u3);
      bf16x8 p1 = frag4(u4, u5, u6, u7);
#pragma unroll
      for (int ks = 0; ks < 2; ++ks) {
        const bf16x8 pf = ks ? p1 : p0;
        const int cg = kb * 4 + ks * 2 + hi;   // 0..7
#pragma unroll
        for (int dt = 0; dt < 2; ++dt) {
          const int row = dt * 32 + q32;
          bf16x8 vf = *(const bf16x8*)(vsc + row * 64 + ((cg ^ (row & 7)) * 8));
          oacc[dt] = mfma32(vf, pf, oacc[dt]);
        }
      }
    }
    __builtin_amdgcn_s_setprio(0);
    __syncthreads();
  }

  // combine partials + cross-half reduce, once
  float lrun = (lr0 + lr1) + (lr2 + lr3);
  lrun += __shfl_xor(lrun, 32, 64);
  const float inv = (lrun > 0.f) ? 1.f / lrun : 0.f;
  bf16_t* crow = ctx + (size_t)(b * 2048 + qabs) * 768 + h * 64;
#pragma unroll
  for (int dt = 0; dt < 2; ++dt)
#pragma unroll
    for (int rq = 0; rq < 4; ++rq) {
      bf16x4 ov = {(bf16_t)(oacc[dt][rq * 4 + 0] * inv),
                   (bf16_t)(oacc[dt][rq * 4 + 1] * inv),
                   (bf16_t)(oacc[dt][rq * 4 + 2] * inv),
                   (bf16_t)(oacc[dt][rq * 4 + 3] * inv)};
      *(bf16x4*)(crow + dt * 32 + rq * 8 + hi * 4) = ov;
    }
}

// ---------------------------------------------------------------------------
// Host launcher
// ---------------------------------------------------------------------------
extern "C" void kernel_launch(void* const* d_in, const int* in_sizes, int n_in,
                              void* d_out, int out_size, void* d_ws, size_t ws_size,
                              hipStream_t stream) {
  const float* x  = (const float*)d_in[0];
  const int* mask = (const int*)d_in[1];
  const float* wq = (const float*)d_in[2];
  const float* wk = (const float*)d_in[3];
  const float* wv = (const float*)d_in[4];
  const float* wo = (const float*)d_in[5];
  const float* bo = (const float*)d_in[6];
  const float* w1 = (const float*)d_in[7];
  const float* w2 = (const float*)d_in[8];
  const float* g1 = (const float*)d_in[9];
  const float* b1 = (const float*)d_in[10];
  const float* g2 = (const float*)d_in[11];
  const float* b2 = (const float*)d_in[12];
  float* out = (float*)d_out;

  char* p = (char*)d_ws;
  bf16_t* WQKVT = (bf16_t*)p; p += (size_t)2304 * 768 * 2;
  bf16_t* WOT   = (bf16_t*)p; p += (size_t)768 * 768 * 2;
  bf16_t* W1T   = (bf16_t*)p; p += (size_t)3072 * 768 * 2;
  bf16_t* W2T   = (bf16_t*)p; p += (size_t)768 * 3072 * 2;
  unsigned int* MB = (unsigned int*)p; p += (size_t)4 * 2048 * 64 * 4;
  bf16_t* Hbuf  = (bf16_t*)p; p += (size_t)8192 * 768 * 2;
  float*  X2    = (float*)p;  p += (size_t)8192 * 768 * 4;
  bf16_t* QKV   = (bf16_t*)p; p += (size_t)8192 * 2304 * 2;
  bf16_t* CTX   = (bf16_t*)p;
  bf16_t* FFN   = QKV;          // overlays QKV (dead by FFN1)
  bf16_t* VT    = (bf16_t*)X2;  // overlays X2 (vT dead before WO writes X2)

  // fused: 6 weight transposes + mask pack + LN1 in one launch
  prep_all<<<6912 + 16384 + 2048, dim3(32, 8), 0, stream>>>(
      wq, wk, wv, wo, w1, w2, WQKVT, mask, MB, x, g1, b1, Hbuf);

  gemm_kernel<false, false, false, false, true, 128><<<dim3(18, 64), 256, 0, stream>>>(
      Hbuf, WQKVT, QKV, nullptr, nullptr, 8192, 2304, 768, VT);
  attn_kernel<<<dim3(48, 16), 256, 0, stream>>>(QKV, VT, MB, CTX);
  gemm_kernel<false, true, true, true, false, 64><<<dim3(12, 64), 256, 0, stream>>>(
      CTX, WOT, X2, bo, x, 8192, 768, 768, nullptr);

  ln_kernel<<<2048, 256, 0, stream>>>(X2, g2, b2, Hbuf);
  gemm_kernel<true, false, false, false, false, 128><<<dim3(24, 64), 256, 0, stream>>>(
      Hbuf, W1T, FFN, nullptr, nullptr, 8192, 3072, 768, nullptr);
  gemm_kernel<false, true, false, true, false, 64><<<dim3(12, 64), 256, 0, stream>>>(
      FFN, W2T, out, nullptr, X2, 8192, 768, 3072, nullptr);
}